// Round 1
// baseline (393.079 us; speedup 1.0000x reference)
//
#include <hip/hip_runtime.h>

#define NN 100000
#define NE 1600000
#define D 128

// ---------------- workspace layout ----------------
static constexpr size_t SUP_BYTES    = (size_t)NN * D * 4;                  // 51,200,000
static constexpr size_t ROWPTR_OFF   = SUP_BYTES;
static constexpr size_t ROWPTR_BYTES = (((size_t)(NN + 1) * 4) + 15) & ~(size_t)15;
static constexpr size_t CUR_OFF      = ROWPTR_OFF + ROWPTR_BYTES;
static constexpr size_t CUR_BYTES    = (((size_t)NN * 4) + 15) & ~(size_t)15;
static constexpr size_t SRCS_OFF     = CUR_OFF + CUR_BYTES;
static constexpr size_t SRCS_BYTES   = (size_t)NE * 4;
static constexpr size_t VALS_OFF     = SRCS_OFF + SRCS_BYTES;
static constexpr size_t VALS_BYTES   = (size_t)NE * 4;
static constexpr size_t CHK_OFF      = VALS_OFF + VALS_BYTES;
static constexpr int    CHUNK        = 256;
static constexpr int    NCH          = (NN + CHUNK - 1) / CHUNK;            // 391
static constexpr size_t CHK_BYTES    = (size_t)NCH * 4;
static constexpr size_t WS_NEEDED    = CHK_OFF + CHK_BYTES;                  // ~64.8 MB

// ---------------- GEMM: support = features @ W ----------------
// block 256 threads; tile = 32 rows x 128 cols; thread: rg = t>>4 -> rows rg*2+{0,1},
// cg = t&15 -> cols cg*8..cg*8+7.  W staged fully in LDS (64KB); features read via L1.
__global__ __launch_bounds__(256) void kgemm(const float* __restrict__ feat,
                                             const float* __restrict__ W,
                                             float* __restrict__ sup) {
  __shared__ float Wl[D * D];
  const int t = threadIdx.x;
  for (int i = t * 4; i < D * D; i += 256 * 4)
    *(float4*)&Wl[i] = *(const float4*)&W[i];
  __syncthreads();

  const int rg = t >> 4;
  const int cg = t & 15;
  const int nTiles = NN / 32;  // 3125
  for (int tile = blockIdx.x; tile < nTiles; tile += gridDim.x) {
    const int r0 = tile * 32 + rg * 2;
    const float* f0 = feat + (size_t)r0 * D;
    const float* f1 = f0 + D;
    float acc0[8], acc1[8];
#pragma unroll
    for (int j = 0; j < 8; ++j) { acc0[j] = 0.f; acc1[j] = 0.f; }

    for (int k = 0; k < D; k += 4) {
      const float4 a4 = *(const float4*)(f0 + k);
      const float4 b4 = *(const float4*)(f1 + k);
      const float* ap = (const float*)&a4;
      const float* bp = (const float*)&b4;
#pragma unroll
      for (int kk = 0; kk < 4; ++kk) {
        const float* wr = &Wl[(k + kk) * D + (cg << 3)];
        float w[8];
        *(float4*)&w[0] = *(const float4*)wr;
        *(float4*)&w[4] = *(const float4*)(wr + 4);
        const float av = ap[kk], bv = bp[kk];
#pragma unroll
        for (int j = 0; j < 8; ++j) {
          acc0[j] = fmaf(av, w[j], acc0[j]);
          acc1[j] = fmaf(bv, w[j], acc1[j]);
        }
      }
    }
    float4* s0 = (float4*)&sup[(size_t)r0 * D + (cg << 3)];
    float4* s1 = (float4*)&sup[(size_t)(r0 + 1) * D + (cg << 3)];
    s0[0] = make_float4(acc0[0], acc0[1], acc0[2], acc0[3]);
    s0[1] = make_float4(acc0[4], acc0[5], acc0[6], acc0[7]);
    s1[0] = make_float4(acc1[0], acc1[1], acc1[2], acc1[3]);
    s1[1] = make_float4(acc1[4], acc1[5], acc1[6], acc1[7]);
  }
}

// ---------------- CSR build ----------------
__global__ __launch_bounds__(256) void khist(const int* __restrict__ dst, int* __restrict__ rowPtr) {
  int e = blockIdx.x * 256 + threadIdx.x;
  if (e < NE) atomicAdd(&rowPtr[1 + dst[e]], 1);
}

__global__ __launch_bounds__(256) void kreduce(const int* __restrict__ rowPtr, int* __restrict__ chk) {
  __shared__ int s[256];
  const int t = threadIdx.x;
  const int i = blockIdx.x * 256 + t;
  s[t] = (i < NN) ? rowPtr[1 + i] : 0;
  __syncthreads();
#pragma unroll
  for (int off = 128; off > 0; off >>= 1) {
    if (t < off) s[t] += s[t + off];
    __syncthreads();
  }
  if (t == 0) chk[blockIdx.x] = s[0];
}

__global__ __launch_bounds__(512) void kscanchunks(int* __restrict__ chk) {
  __shared__ int s[512];
  const int t = threadIdx.x;
  const int v = (t < NCH) ? chk[t] : 0;
  s[t] = v;
  __syncthreads();
#pragma unroll
  for (int off = 1; off < 512; off <<= 1) {
    int x = (t >= off) ? s[t - off] : 0;
    __syncthreads();
    s[t] += x;
    __syncthreads();
  }
  if (t < NCH) chk[t] = s[t] - v;  // exclusive prefix of chunk sums
}

__global__ __launch_bounds__(256) void kscanfinal(int* __restrict__ rowPtr, int* __restrict__ cursor,
                                                  const int* __restrict__ chk) {
  __shared__ int s[256];
  const int t = threadIdx.x;
  const int i = blockIdx.x * 256 + t;
  const int v = (i < NN) ? rowPtr[1 + i] : 0;
  s[t] = v;
  __syncthreads();
#pragma unroll
  for (int off = 1; off < 256; off <<= 1) {
    int x = (t >= off) ? s[t - off] : 0;
    __syncthreads();
    s[t] += x;
    __syncthreads();
  }
  if (i < NN) {
    const int base = chk[blockIdx.x];
    const int incl = s[t];
    rowPtr[1 + i] = base + incl;      // inclusive cumulative degree
    cursor[i]     = base + incl - v;  // exclusive start = rowPtr[i]
  }
}

__global__ __launch_bounds__(256) void kfill(const int* __restrict__ src, const int* __restrict__ dst,
                                             const float* __restrict__ val, int* __restrict__ cursor,
                                             int* __restrict__ srcS, float* __restrict__ valS) {
  int e = blockIdx.x * 256 + threadIdx.x;
  if (e >= NE) return;
  const int d0 = dst[e];
  const int pos = atomicAdd(&cursor[d0], 1);
  srcS[pos] = src[e];
  valS[pos] = val[e];
}

// ---------------- gather-aggregate + epilogue ----------------
// one wave per node; lane owns columns {2*lane, 2*lane+1}
__global__ __launch_bounds__(256) void kgather(const float* __restrict__ sup,
                                               const int* __restrict__ rowPtr,
                                               const int* __restrict__ srcS,
                                               const float* __restrict__ valS,
                                               const float* __restrict__ feat,
                                               const float* __restrict__ bias,
                                               float* __restrict__ out) {
  const int n = blockIdx.x * 4 + (threadIdx.x >> 6);
  if (n >= NN) return;
  const int lane = threadIdx.x & 63;
  const int beg = rowPtr[n];
  const int end = rowPtr[n + 1];
  float ax = 0.f, ay = 0.f;
  for (int base = beg; base < end; base += 64) {
    int cnt = end - base;
    if (cnt > 64) cnt = 64;
    int s = 0;
    float v = 0.f;
    if (lane < cnt) {
      s = srcS[base + lane];
      v = valS[base + lane];
    }
#pragma unroll 4
    for (int i = 0; i < cnt; ++i) {
      const int si = __shfl(s, i);
      const float vi = __shfl(v, i);
      const float2 sv = *(const float2*)(sup + (size_t)si * D + (lane << 1));
      ax = fmaf(sv.x, vi, ax);
      ay = fmaf(sv.y, vi, ay);
    }
  }
  const float2 bb = *(const float2*)(bias + (lane << 1));
  const float2 ft = *(const float2*)(feat + (size_t)n * D + (lane << 1));
  float2 o;
  o.x = fmaxf(ax + bb.x, 0.f) + ft.x;
  o.y = fmaxf(ay + bb.y, 0.f) + ft.y;
  *(float2*)(out + (size_t)n * D + (lane << 1)) = o;
}

// ---------------- fallback: atomic scatter (if ws too small for CSR) ----------------
__global__ __launch_bounds__(256) void kscatter(const float* __restrict__ sup,
                                                const int* __restrict__ src,
                                                const int* __restrict__ dst,
                                                const float* __restrict__ val,
                                                float* __restrict__ out) {
  const long long t = (long long)blockIdx.x * 256 + threadIdx.x;
  const int e = (int)(t >> 5);
  if (e >= NE) return;
  const int q = (int)(t & 31);
  const int s = src[e];
  const int d0 = dst[e];
  const float v = val[e];
  const float4 sv = *(const float4*)(sup + (size_t)s * D + (q << 2));
  float* op = out + (size_t)d0 * D + (q << 2);
  atomicAdd(op + 0, sv.x * v);
  atomicAdd(op + 1, sv.y * v);
  atomicAdd(op + 2, sv.z * v);
  atomicAdd(op + 3, sv.w * v);
}

__global__ __launch_bounds__(256) void kfinal(float* __restrict__ out, const float* __restrict__ feat,
                                              const float* __restrict__ bias) {
  const long long t = (long long)blockIdx.x * 256 + threadIdx.x;
  if (t >= (long long)NN * D / 4) return;
  float4 o = ((float4*)out)[t];
  const float4 f = ((const float4*)feat)[t];
  const int col = (int)((t * 4) & (D - 1));
  const float4 bb = *(const float4*)(bias + col);
  o.x = fmaxf(o.x + bb.x, 0.f) + f.x;
  o.y = fmaxf(o.y + bb.y, 0.f) + f.y;
  o.z = fmaxf(o.z + bb.z, 0.f) + f.z;
  o.w = fmaxf(o.w + bb.w, 0.f) + f.w;
  ((float4*)out)[t] = o;
}

extern "C" void kernel_launch(void* const* d_in, const int* in_sizes, int n_in,
                              void* d_out, int out_size, void* d_ws, size_t ws_size,
                              hipStream_t stream) {
  const float* feat = (const float*)d_in[0];
  const int*   esrc = (const int*)d_in[1];
  const int*   edst = (const int*)d_in[2];
  const float* eval = (const float*)d_in[3];
  const float* W    = (const float*)d_in[4];
  const float* bias = (const float*)d_in[5];
  float* out = (float*)d_out;
  char*  ws  = (char*)d_ws;

  float* sup = (float*)ws;

  // GEMM: support = features @ W
  kgemm<<<1024, 256, 0, stream>>>(feat, W, sup);

  if (ws_size >= WS_NEEDED) {
    int*   rowPtr = (int*)(ws + ROWPTR_OFF);
    int*   cursor = (int*)(ws + CUR_OFF);
    int*   srcS   = (int*)(ws + SRCS_OFF);
    float* valS   = (float*)(ws + VALS_OFF);
    int*   chk    = (int*)(ws + CHK_OFF);

    hipMemsetAsync(rowPtr, 0, (size_t)(NN + 1) * 4, stream);
    khist<<<(NE + 255) / 256, 256, 0, stream>>>(edst, rowPtr);
    kreduce<<<NCH, 256, 0, stream>>>(rowPtr, chk);
    kscanchunks<<<1, 512, 0, stream>>>(chk);
    kscanfinal<<<NCH, 256, 0, stream>>>(rowPtr, cursor, chk);
    kfill<<<(NE + 255) / 256, 256, 0, stream>>>(esrc, edst, eval, cursor, srcS, valS);
    kgather<<<(NN + 3) / 4, 256, 0, stream>>>(sup, rowPtr, srcS, valS, feat, bias, out);
  } else {
    // fallback: atomic scatter into out
    hipMemsetAsync(out, 0, (size_t)NN * D * 4, stream);
    kscatter<<<(int)(((long long)NE * 32 + 255) / 256), 256, 0, stream>>>(sup, esrc, edst, eval, out);
    kfinal<<<(int)(((long long)NN * D / 4 + 255) / 256), 256, 0, stream>>>(out, feat, bias);
  }
}

// Round 2
// 333.214 us; speedup vs baseline: 1.1797x; 1.1797x over previous
//
#include <hip/hip_runtime.h>
#include <hip/hip_bf16.h>

#define NN 100000
#define NE 1600000
#define D 128

// ---------------- workspace layout ----------------
static constexpr size_t SUP_BYTES    = ((size_t)NN * D * 2 + 15) & ~(size_t)15;   // bf16 support, 25.6 MB
static constexpr size_t ROWPTR_OFF   = SUP_BYTES;
static constexpr size_t ROWPTR_BYTES = (((size_t)(NN + 1) * 4) + 15) & ~(size_t)15;
static constexpr size_t CUR_OFF      = ROWPTR_OFF + ROWPTR_BYTES;
static constexpr size_t CUR_BYTES    = (((size_t)NN * 4) + 15) & ~(size_t)15;
static constexpr size_t EDG_OFF      = CUR_OFF + CUR_BYTES;
static constexpr size_t EDG_BYTES    = (size_t)NE * 8;                            // packed {src,val}
static constexpr size_t CHK_OFF      = EDG_OFF + EDG_BYTES;
static constexpr int    CHUNK        = 256;
static constexpr int    NCH          = (NN + CHUNK - 1) / CHUNK;                  // 391
static constexpr size_t CHK_BYTES    = (size_t)NCH * 4;
static constexpr size_t WS_NEEDED    = CHK_OFF + CHK_BYTES;                       // ~39 MB

__device__ __forceinline__ unsigned pk_bf16(float a, float b) {
  __hip_bfloat16 x = __float2bfloat16(a), y = __float2bfloat16(b);
  return (unsigned)*(unsigned short*)&x | ((unsigned)*(unsigned short*)&y << 16);
}

// ---------------- GEMM: support = features @ W  (fp32 compute, bf16 out) ----------------
__global__ __launch_bounds__(256) void kgemm(const float* __restrict__ feat,
                                             const float* __restrict__ W,
                                             unsigned short* __restrict__ sup) {
  __shared__ float Wl[D * D];
  const int t = threadIdx.x;
  for (int i = t * 4; i < D * D; i += 256 * 4)
    *(float4*)&Wl[i] = *(const float4*)&W[i];
  __syncthreads();

  const int rg = t >> 4;
  const int cg = t & 15;
  const int nTiles = NN / 32;  // 3125
  for (int tile = blockIdx.x; tile < nTiles; tile += gridDim.x) {
    const int r0 = tile * 32 + rg * 2;
    const float* f0 = feat + (size_t)r0 * D;
    const float* f1 = f0 + D;
    float acc0[8], acc1[8];
#pragma unroll
    for (int j = 0; j < 8; ++j) { acc0[j] = 0.f; acc1[j] = 0.f; }

    for (int k = 0; k < D; k += 4) {
      const float4 a4 = *(const float4*)(f0 + k);
      const float4 b4 = *(const float4*)(f1 + k);
      const float* ap = (const float*)&a4;
      const float* bp = (const float*)&b4;
#pragma unroll
      for (int kk = 0; kk < 4; ++kk) {
        const float* wr = &Wl[(k + kk) * D + (cg << 3)];
        float w[8];
        *(float4*)&w[0] = *(const float4*)wr;
        *(float4*)&w[4] = *(const float4*)(wr + 4);
        const float av = ap[kk], bv = bp[kk];
#pragma unroll
        for (int j = 0; j < 8; ++j) {
          acc0[j] = fmaf(av, w[j], acc0[j]);
          acc1[j] = fmaf(bv, w[j], acc1[j]);
        }
      }
    }
    uint4 p0 = make_uint4(pk_bf16(acc0[0], acc0[1]), pk_bf16(acc0[2], acc0[3]),
                          pk_bf16(acc0[4], acc0[5]), pk_bf16(acc0[6], acc0[7]));
    uint4 p1 = make_uint4(pk_bf16(acc1[0], acc1[1]), pk_bf16(acc1[2], acc1[3]),
                          pk_bf16(acc1[4], acc1[5]), pk_bf16(acc1[6], acc1[7]));
    *(uint4*)&sup[(size_t)r0 * D + (cg << 3)] = p0;
    *(uint4*)&sup[(size_t)(r0 + 1) * D + (cg << 3)] = p1;
  }
}

// ---------------- CSR build ----------------
__global__ __launch_bounds__(256) void khist(const int* __restrict__ dst, int* __restrict__ rowPtr) {
  int e = blockIdx.x * 256 + threadIdx.x;
  if (e < NE) atomicAdd(&rowPtr[1 + dst[e]], 1);
}

__global__ __launch_bounds__(256) void kreduce(const int* __restrict__ rowPtr, int* __restrict__ chk) {
  __shared__ int s[256];
  const int t = threadIdx.x;
  const int i = blockIdx.x * 256 + t;
  s[t] = (i < NN) ? rowPtr[1 + i] : 0;
  __syncthreads();
#pragma unroll
  for (int off = 128; off > 0; off >>= 1) {
    if (t < off) s[t] += s[t + off];
    __syncthreads();
  }
  if (t == 0) chk[blockIdx.x] = s[0];
}

__global__ __launch_bounds__(512) void kscanchunks(int* __restrict__ chk) {
  __shared__ int s[512];
  const int t = threadIdx.x;
  const int v = (t < NCH) ? chk[t] : 0;
  s[t] = v;
  __syncthreads();
#pragma unroll
  for (int off = 1; off < 512; off <<= 1) {
    int x = (t >= off) ? s[t - off] : 0;
    __syncthreads();
    s[t] += x;
    __syncthreads();
  }
  if (t < NCH) chk[t] = s[t] - v;  // exclusive prefix of chunk sums
}

__global__ __launch_bounds__(256) void kscanfinal(int* __restrict__ rowPtr, int* __restrict__ cursor,
                                                  const int* __restrict__ chk) {
  __shared__ int s[256];
  const int t = threadIdx.x;
  const int i = blockIdx.x * 256 + t;
  const int v = (i < NN) ? rowPtr[1 + i] : 0;
  s[t] = v;
  __syncthreads();
#pragma unroll
  for (int off = 1; off < 256; off <<= 1) {
    int x = (t >= off) ? s[t - off] : 0;
    __syncthreads();
    s[t] += x;
    __syncthreads();
  }
  if (i < NN) {
    const int base = chk[blockIdx.x];
    const int incl = s[t];
    rowPtr[1 + i] = base + incl;      // inclusive cumulative degree
    cursor[i]     = base + incl - v;  // exclusive start = rowPtr[i]
  }
}

__global__ __launch_bounds__(256) void kfill(const int* __restrict__ src, const int* __restrict__ dst,
                                             const float* __restrict__ val, int* __restrict__ cursor,
                                             long long* __restrict__ edges) {
  int e = blockIdx.x * 256 + threadIdx.x;
  if (e >= NE) return;
  const int d0 = dst[e];
  const int pos = atomicAdd(&cursor[d0], 1);
  edges[pos] = (long long)(unsigned)src[e] | ((long long)__float_as_uint(val[e]) << 32);
}

// ---------------- gather-aggregate + epilogue ----------------
// 16-lane group per node; lane owns 8 cols (one dwordx4 of bf16x8); 4 nodes/wave.
__global__ __launch_bounds__(256) void kgather(const unsigned short* __restrict__ sup,
                                               const int* __restrict__ rowPtr,
                                               const long long* __restrict__ edges,
                                               const float* __restrict__ feat,
                                               const float* __restrict__ bias,
                                               float* __restrict__ out) {
  const int n = blockIdx.x * 16 + (threadIdx.x >> 4);
  if (n >= NN) return;
  const int gl = threadIdx.x & 15;
  const int beg = rowPtr[n];
  const int end = rowPtr[n + 1];
  float a0 = 0.f, a1 = 0.f, a2 = 0.f, a3 = 0.f, a4 = 0.f, a5 = 0.f, a6 = 0.f, a7 = 0.f;

  for (int base = beg; base < end; base += 16) {
    int cnt = end - base;
    if (cnt > 16) cnt = 16;
    int es = 0, evb = 0;
    if (gl < cnt) {
      const long long e = edges[base + gl];
      es = (int)e;
      evb = (int)(e >> 32);
    }
#pragma unroll 4
    for (int i = 0; i < cnt; ++i) {
      const int si = __shfl(es, i, 16);
      const float vi = __uint_as_float((unsigned)__shfl(evb, i, 16));
      const uint4 r = *(const uint4*)(sup + (size_t)si * D + (gl << 3));
      a0 = fmaf(__uint_as_float(r.x << 16), vi, a0);
      a1 = fmaf(__uint_as_float(r.x & 0xffff0000u), vi, a1);
      a2 = fmaf(__uint_as_float(r.y << 16), vi, a2);
      a3 = fmaf(__uint_as_float(r.y & 0xffff0000u), vi, a3);
      a4 = fmaf(__uint_as_float(r.z << 16), vi, a4);
      a5 = fmaf(__uint_as_float(r.z & 0xffff0000u), vi, a5);
      a6 = fmaf(__uint_as_float(r.w << 16), vi, a6);
      a7 = fmaf(__uint_as_float(r.w & 0xffff0000u), vi, a7);
    }
  }

  const int c = gl << 3;
  const float4 b0 = *(const float4*)(bias + c);
  const float4 b1 = *(const float4*)(bias + c + 4);
  const float* fr = feat + (size_t)n * D + c;
  const float4 f0 = *(const float4*)fr;
  const float4 f1 = *(const float4*)(fr + 4);
  float4 o0, o1;
  o0.x = fmaxf(a0 + b0.x, 0.f) + f0.x;
  o0.y = fmaxf(a1 + b0.y, 0.f) + f0.y;
  o0.z = fmaxf(a2 + b0.z, 0.f) + f0.z;
  o0.w = fmaxf(a3 + b0.w, 0.f) + f0.w;
  o1.x = fmaxf(a4 + b1.x, 0.f) + f1.x;
  o1.y = fmaxf(a5 + b1.y, 0.f) + f1.y;
  o1.z = fmaxf(a6 + b1.z, 0.f) + f1.z;
  o1.w = fmaxf(a7 + b1.w, 0.f) + f1.w;
  float* orow = out + (size_t)n * D + c;
  *(float4*)orow = o0;
  *(float4*)(orow + 4) = o1;
}

extern "C" void kernel_launch(void* const* d_in, const int* in_sizes, int n_in,
                              void* d_out, int out_size, void* d_ws, size_t ws_size,
                              hipStream_t stream) {
  const float* feat = (const float*)d_in[0];
  const int*   esrc = (const int*)d_in[1];
  const int*   edst = (const int*)d_in[2];
  const float* eval = (const float*)d_in[3];
  const float* W    = (const float*)d_in[4];
  const float* bias = (const float*)d_in[5];
  float* out = (float*)d_out;
  char*  ws  = (char*)d_ws;

  unsigned short* sup    = (unsigned short*)ws;
  int*            rowPtr = (int*)(ws + ROWPTR_OFF);
  int*            cursor = (int*)(ws + CUR_OFF);
  long long*      edges  = (long long*)(ws + EDG_OFF);
  int*            chk    = (int*)(ws + CHK_OFF);

  // GEMM: support = features @ W  (bf16 out)
  kgemm<<<1024, 256, 0, stream>>>(feat, W, sup);

  // CSR build
  hipMemsetAsync(rowPtr, 0, (size_t)(NN + 1) * 4, stream);
  khist<<<(NE + 255) / 256, 256, 0, stream>>>(edst, rowPtr);
  kreduce<<<NCH, 256, 0, stream>>>(rowPtr, chk);
  kscanchunks<<<1, 512, 0, stream>>>(chk);
  kscanfinal<<<NCH, 256, 0, stream>>>(rowPtr, cursor, chk);
  kfill<<<(NE + 255) / 256, 256, 0, stream>>>(esrc, edst, eval, cursor, edges);

  // gather-aggregate + bias + relu + residual
  kgather<<<(NN + 15) / 16, 256, 0, stream>>>(sup, rowPtr, edges, feat, bias, out);
}

// Round 3
// 203.586 us; speedup vs baseline: 1.9308x; 1.6367x over previous
//
#include <hip/hip_runtime.h>
#include <hip/hip_bf16.h>

#define NN 100000
#define NE 1600000
#define D 128
#define NB 196   // buckets of 512 nodes (dst >> 9)
#define BSH 9

// ---------------- workspace layout ----------------
static constexpr size_t SUP_OFF    = 0;
static constexpr size_t SUP_BYTES  = (((size_t)NN * D * 2) + 15) & ~(size_t)15;   // 25.6 MB bf16
static constexpr size_t ROWPTR_OFF = SUP_OFF + SUP_BYTES;
static constexpr size_t ROWPTR_BY  = (((size_t)(NN + 1) * 4) + 15) & ~(size_t)15;
static constexpr size_t CNT_OFF    = ROWPTR_OFF + ROWPTR_BY;
static constexpr size_t CNT_BY     = (((size_t)NB * 4) + 15) & ~(size_t)15;
static constexpr size_t BB_OFF     = CNT_OFF + CNT_BY;
static constexpr size_t BB_BY      = (((size_t)(NB + 1) * 4) + 15) & ~(size_t)15;
static constexpr size_t CURA_OFF   = BB_OFF + BB_BY;
static constexpr size_t CURA_BY    = (((size_t)NB * 4) + 15) & ~(size_t)15;
static constexpr size_t STG_OFF    = CURA_OFF + CURA_BY;
static constexpr size_t STG_BY     = (size_t)NE * 8;                               // 12.8 MB
static constexpr size_t EDG_OFF    = STG_OFF + STG_BY;
static constexpr size_t EDG_BY     = (size_t)NE * 8;                               // 12.8 MB
// total ~51.6 MB (R0's 64.8 MB CSR path ran, so ws_size covers this)

__device__ __forceinline__ unsigned pk_bf16(float a, float b) {
  __hip_bfloat16 x = __float2bfloat16(a), y = __float2bfloat16(b);
  return (unsigned)*(unsigned short*)&x | ((unsigned)*(unsigned short*)&y << 16);
}

// ---------------- GEMM: support = features @ W  (fp32 compute, bf16 out) ----------------
__global__ __launch_bounds__(256) void kgemm(const float* __restrict__ feat,
                                             const float* __restrict__ W,
                                             unsigned short* __restrict__ sup) {
  __shared__ float Wl[D * D];
  const int t = threadIdx.x;
  for (int i = t * 4; i < D * D; i += 256 * 4)
    *(float4*)&Wl[i] = *(const float4*)&W[i];
  __syncthreads();

  const int rg = t >> 4;
  const int cg = t & 15;
  const int nTiles = NN / 32;  // 3125
  for (int tile = blockIdx.x; tile < nTiles; tile += gridDim.x) {
    const int r0 = tile * 32 + rg * 2;
    const float* f0 = feat + (size_t)r0 * D;
    const float* f1 = f0 + D;
    float acc0[8], acc1[8];
#pragma unroll
    for (int j = 0; j < 8; ++j) { acc0[j] = 0.f; acc1[j] = 0.f; }

    for (int k = 0; k < D; k += 4) {
      const float4 a4 = *(const float4*)(f0 + k);
      const float4 b4 = *(const float4*)(f1 + k);
      const float* ap = (const float*)&a4;
      const float* bp = (const float*)&b4;
#pragma unroll
      for (int kk = 0; kk < 4; ++kk) {
        const float* wr = &Wl[(k + kk) * D + (cg << 3)];
        float w[8];
        *(float4*)&w[0] = *(const float4*)wr;
        *(float4*)&w[4] = *(const float4*)(wr + 4);
        const float av = ap[kk], bv = bp[kk];
#pragma unroll
        for (int j = 0; j < 8; ++j) {
          acc0[j] = fmaf(av, w[j], acc0[j]);
          acc1[j] = fmaf(bv, w[j], acc1[j]);
        }
      }
    }
    uint4 p0 = make_uint4(pk_bf16(acc0[0], acc0[1]), pk_bf16(acc0[2], acc0[3]),
                          pk_bf16(acc0[4], acc0[5]), pk_bf16(acc0[6], acc0[7]));
    uint4 p1 = make_uint4(pk_bf16(acc1[0], acc1[1]), pk_bf16(acc1[2], acc1[3]),
                          pk_bf16(acc1[4], acc1[5]), pk_bf16(acc1[6], acc1[7]));
    *(uint4*)&sup[(size_t)r0 * D + (cg << 3)] = p0;
    *(uint4*)&sup[(size_t)(r0 + 1) * D + (cg << 3)] = p1;
  }
}

// ---------------- bucket histogram (196 counters, LDS pre-aggregated) ----------------
__global__ __launch_bounds__(256) void kbhist(const int* __restrict__ dst, int* __restrict__ cnt) {
  __shared__ int h[NB];
  const int t = threadIdx.x;
  for (int i = t; i < NB; i += 256) h[i] = 0;
  __syncthreads();
  const int e0 = blockIdx.x * 4096;
#pragma unroll
  for (int k = 0; k < 16; ++k) {
    const int e = e0 + t + k * 256;
    if (e < NE) atomicAdd(&h[dst[e] >> BSH], 1);
  }
  __syncthreads();
  for (int i = t; i < NB; i += 256) {
    const int c = h[i];
    if (c) atomicAdd(&cnt[i], c);
  }
}

// ---------------- tiny scan over NB buckets ----------------
__global__ __launch_bounds__(256) void kscanNB(const int* __restrict__ cnt,
                                               int* __restrict__ bucketBase,
                                               int* __restrict__ cursorA) {
  __shared__ int s[256];
  const int t = threadIdx.x;
  const int v = (t < NB) ? cnt[t] : 0;
  s[t] = v;
  __syncthreads();
#pragma unroll
  for (int off = 1; off < 256; off <<= 1) {
    const int x = (t >= off) ? s[t - off] : 0;
    __syncthreads();
    s[t] += x;
    __syncthreads();
  }
  if (t < NB) {
    const int excl = s[t] - v;
    bucketBase[t] = excl;
    cursorA[t] = excl;
  }
  if (t == 0) bucketBase[NB] = NE;
}

// ---------------- pass A: multisplit into buckets ----------------
// packed stg word: lo = src | (dst&511)<<17 ; hi = val bits
__global__ __launch_bounds__(256) void kpassA(const int* __restrict__ src,
                                              const int* __restrict__ dst,
                                              const float* __restrict__ val,
                                              int* __restrict__ cursorA,
                                              unsigned long long* __restrict__ stg) {
  __shared__ int h[NB];
  __shared__ int base[NB];
  const int t = threadIdx.x;
  for (int i = t; i < NB; i += 256) h[i] = 0;
  __syncthreads();
  const int e0 = blockIdx.x * 4096;
  int d[16];
#pragma unroll
  for (int k = 0; k < 16; ++k) {
    const int e = e0 + t + k * 256;
    d[k] = (e < NE) ? dst[e] : -1;
    if (d[k] >= 0) atomicAdd(&h[d[k] >> BSH], 1);
  }
  __syncthreads();
  for (int i = t; i < NB; i += 256)
    base[i] = h[i] ? atomicAdd(&cursorA[i], h[i]) : 0;
  __syncthreads();
#pragma unroll
  for (int k = 0; k < 16; ++k) {
    const int e = e0 + t + k * 256;
    if (d[k] >= 0) {
      const int b = d[k] >> BSH;
      const int pos = atomicAdd(&base[b], 1);
      const unsigned lo = (unsigned)src[e] | ((unsigned)(d[k] & 511) << 17);
      const unsigned hi = __float_as_uint(val[e]);
      stg[pos] = (unsigned long long)lo | ((unsigned long long)hi << 32);
    }
  }
}

// ---------------- pass B: per-bucket exact CSR (one block per bucket) ----------------
// final edge word: lo = src ; hi = val bits
__global__ __launch_bounds__(256) void kpassB(const unsigned long long* __restrict__ stg,
                                              const int* __restrict__ bucketBase,
                                              int* __restrict__ rowPtr,
                                              unsigned long long* __restrict__ edges) {
  __shared__ int hist[512];
  __shared__ int start[512];
  __shared__ int psum[256];
  const int b = blockIdx.x;
  const int t = threadIdx.x;
  const int beg = bucketBase[b], end = bucketBase[b + 1];
  hist[t] = 0;
  hist[t + 256] = 0;
  __syncthreads();
  for (int i = beg + t; i < end; i += 256)
    atomicAdd(&hist[((unsigned)stg[i] >> 17) & 511], 1);
  __syncthreads();
  const int h0 = hist[2 * t], h1 = hist[2 * t + 1];
  const int p = h0 + h1;
  psum[t] = p;
  __syncthreads();
#pragma unroll
  for (int off = 1; off < 256; off <<= 1) {
    const int x = (t >= off) ? psum[t - off] : 0;
    __syncthreads();
    psum[t] += x;
    __syncthreads();
  }
  const int ex = psum[t] - p;
  start[2 * t] = ex;
  start[2 * t + 1] = ex + h0;
  __syncthreads();
  const int node0 = b << BSH;
  for (int j = t; j < 512; j += 256) {
    const int node = node0 + j;
    if (node < NN) rowPtr[node] = beg + start[j];
  }
  if (b == NB - 1 && t == 0) rowPtr[NN] = NE;
  for (int j = t; j < 512; j += 256) hist[j] = start[j];  // reuse as cursors
  __syncthreads();
  for (int i = beg + t; i < end; i += 256) {
    const unsigned long long pk = stg[i];
    const unsigned lo = (unsigned)pk;
    const int dl = (lo >> 17) & 511;
    const int pos = beg + atomicAdd(&hist[dl], 1);
    edges[pos] = (pk & 0xFFFFFFFF00000000ull) | (unsigned long long)(lo & 0x1FFFFu);
  }
}

// ---------------- gather-aggregate + epilogue ----------------
// 16-lane group per node; lane owns 8 cols (one dwordx4 of bf16x8); 4 nodes/wave.
__global__ __launch_bounds__(256) void kgather(const unsigned short* __restrict__ sup,
                                               const int* __restrict__ rowPtr,
                                               const long long* __restrict__ edges,
                                               const float* __restrict__ feat,
                                               const float* __restrict__ bias,
                                               float* __restrict__ out) {
  const int n = blockIdx.x * 16 + (threadIdx.x >> 4);
  if (n >= NN) return;
  const int gl = threadIdx.x & 15;
  const int beg = rowPtr[n];
  const int end = rowPtr[n + 1];
  float a0 = 0.f, a1 = 0.f, a2 = 0.f, a3 = 0.f, a4 = 0.f, a5 = 0.f, a6 = 0.f, a7 = 0.f;

  for (int base = beg; base < end; base += 16) {
    int cnt = end - base;
    if (cnt > 16) cnt = 16;
    int es = 0, evb = 0;
    if (gl < cnt) {
      const long long e = edges[base + gl];
      es = (int)e;
      evb = (int)(e >> 32);
    }
#pragma unroll 4
    for (int i = 0; i < cnt; ++i) {
      const int si = __shfl(es, i, 16);
      const float vi = __uint_as_float((unsigned)__shfl(evb, i, 16));
      const uint4 r = *(const uint4*)(sup + (size_t)si * D + (gl << 3));
      a0 = fmaf(__uint_as_float(r.x << 16), vi, a0);
      a1 = fmaf(__uint_as_float(r.x & 0xffff0000u), vi, a1);
      a2 = fmaf(__uint_as_float(r.y << 16), vi, a2);
      a3 = fmaf(__uint_as_float(r.y & 0xffff0000u), vi, a3);
      a4 = fmaf(__uint_as_float(r.z << 16), vi, a4);
      a5 = fmaf(__uint_as_float(r.z & 0xffff0000u), vi, a5);
      a6 = fmaf(__uint_as_float(r.w << 16), vi, a6);
      a7 = fmaf(__uint_as_float(r.w & 0xffff0000u), vi, a7);
    }
  }

  const int c = gl << 3;
  const float4 b0 = *(const float4*)(bias + c);
  const float4 b1 = *(const float4*)(bias + c + 4);
  const float* fr = feat + (size_t)n * D + c;
  const float4 f0 = *(const float4*)fr;
  const float4 f1 = *(const float4*)(fr + 4);
  float4 o0, o1;
  o0.x = fmaxf(a0 + b0.x, 0.f) + f0.x;
  o0.y = fmaxf(a1 + b0.y, 0.f) + f0.y;
  o0.z = fmaxf(a2 + b0.z, 0.f) + f0.z;
  o0.w = fmaxf(a3 + b0.w, 0.f) + f0.w;
  o1.x = fmaxf(a4 + b1.x, 0.f) + f1.x;
  o1.y = fmaxf(a5 + b1.y, 0.f) + f1.y;
  o1.z = fmaxf(a6 + b1.z, 0.f) + f1.z;
  o1.w = fmaxf(a7 + b1.w, 0.f) + f1.w;
  float* orow = out + (size_t)n * D + c;
  *(float4*)orow = o0;
  *(float4*)(orow + 4) = o1;
}

extern "C" void kernel_launch(void* const* d_in, const int* in_sizes, int n_in,
                              void* d_out, int out_size, void* d_ws, size_t ws_size,
                              hipStream_t stream) {
  const float* feat = (const float*)d_in[0];
  const int*   esrc = (const int*)d_in[1];
  const int*   edst = (const int*)d_in[2];
  const float* eval = (const float*)d_in[3];
  const float* W    = (const float*)d_in[4];
  const float* bias = (const float*)d_in[5];
  float* out = (float*)d_out;
  char*  ws  = (char*)d_ws;

  unsigned short*     sup        = (unsigned short*)(ws + SUP_OFF);
  int*                rowPtr     = (int*)(ws + ROWPTR_OFF);
  int*                cnt        = (int*)(ws + CNT_OFF);
  int*                bucketBase = (int*)(ws + BB_OFF);
  int*                cursorA    = (int*)(ws + CURA_OFF);
  unsigned long long* stg        = (unsigned long long*)(ws + STG_OFF);
  unsigned long long* edges      = (unsigned long long*)(ws + EDG_OFF);

  // GEMM: support = features @ W  (bf16 out)
  kgemm<<<1024, 256, 0, stream>>>(feat, W, sup);

  // CSR build via two-level bucket sort
  hipMemsetAsync(cnt, 0, CNT_BY, stream);
  const int nA = (NE + 4095) / 4096;  // 391
  kbhist<<<nA, 256, 0, stream>>>(edst, cnt);
  kscanNB<<<1, 256, 0, stream>>>(cnt, bucketBase, cursorA);
  kpassA<<<nA, 256, 0, stream>>>(esrc, edst, eval, cursorA, stg);
  kpassB<<<NB, 256, 0, stream>>>(stg, bucketBase, rowPtr, edges);

  // gather-aggregate + bias + relu + residual
  kgather<<<(NN + 15) / 16, 256, 0, stream>>>(sup, rowPtr, (const long long*)edges, feat, bias, out);
}

// Round 4
// 160.836 us; speedup vs baseline: 2.4440x; 1.2658x over previous
//
#include <hip/hip_runtime.h>
#include <hip/hip_bf16.h>

#define NN 100000
#define NE 1600000
#define D 128
#define NB 196   // buckets of 512 nodes (dst >> 9)
#define BSH 9

// ---------------- workspace layout ----------------
static constexpr size_t SUP_OFF    = 0;
static constexpr size_t SUP_BYTES  = (((size_t)NN * D * 2) + 15) & ~(size_t)15;   // 25.6 MB bf16
static constexpr size_t ROWPTR_OFF = SUP_OFF + SUP_BYTES;
static constexpr size_t ROWPTR_BY  = (((size_t)(NN + 1) * 4) + 15) & ~(size_t)15;
static constexpr size_t CNT_OFF    = ROWPTR_OFF + ROWPTR_BY;
static constexpr size_t CNT_BY     = (((size_t)NB * 4) + 15) & ~(size_t)15;
static constexpr size_t BB_OFF     = CNT_OFF + CNT_BY;
static constexpr size_t BB_BY      = (((size_t)(NB + 1) * 4) + 15) & ~(size_t)15;
static constexpr size_t CURA_OFF   = BB_OFF + BB_BY;
static constexpr size_t CURA_BY    = (((size_t)NB * 4) + 15) & ~(size_t)15;
static constexpr size_t WT_OFF     = CURA_OFF + CURA_BY;
static constexpr size_t WT_BY      = (size_t)D * D * 2;                            // 32 KB bf16 W^T
static constexpr size_t STG_OFF    = WT_OFF + WT_BY;
static constexpr size_t STG_BY     = (size_t)NE * 8;                               // 12.8 MB
static constexpr size_t EDG_OFF    = STG_OFF + STG_BY;
static constexpr size_t EDG_BY     = (size_t)NE * 8;                               // 12.8 MB

typedef __attribute__((ext_vector_type(8))) short short8v;   // 8 bf16 (4 VGPRs)
typedef __attribute__((ext_vector_type(4))) float float4v;   // MFMA C/D

__device__ __forceinline__ unsigned pk_bf16(float a, float b) {
  __hip_bfloat16 x = __float2bfloat16(a), y = __float2bfloat16(b);
  return (unsigned)*(unsigned short*)&x | ((unsigned)*(unsigned short*)&y << 16);
}

// ---------------- W prep: Wt[col][k] = bf16(W[k][col]) ----------------
__global__ __launch_bounds__(256) void kwconv(const float* __restrict__ W,
                                              unsigned short* __restrict__ Wt) {
  const int i = blockIdx.x * 256 + threadIdx.x;
  if (i < D * D) {
    const int k = i >> 7, c = i & 127;
    __hip_bfloat16 h = __float2bfloat16(W[i]);
    Wt[c * D + k] = *(unsigned short*)&h;
  }
}

// ---------------- GEMM: support = feat @ W via MFMA bf16 ----------------
// block: 4 waves x 16 rows = 64 rows, full 128 cols.
// A frag (16x32): lane l holds feat[row = l&15][k = ks*32 + (l>>4)*8 + j], j=0..7
// B frag (32x16): lane l holds W[k = ks*32 + (l>>4)*8 + j][col = ct*16 + (l&15)]
//                 read from Wt[col][k] (k-contiguous), LDS XOR-swizzled.
// C/D: col = lane&15, row = (lane>>4)*4 + reg   [guide §3, verified m89/m91]
__global__ __launch_bounds__(256) void kgemm(const float* __restrict__ feat,
                                             const unsigned short* __restrict__ Wt,
                                             unsigned short* __restrict__ sup) {
  __shared__ char Wl[32768];
  const int t = threadIdx.x;
  // stage Wt -> LDS with st-style XOR swizzle: byte ^= ((row&7)<<4), row = byte>>8
  {
    const uint4* g = (const uint4*)Wt;
    for (int i = t; i < 2048; i += 256) {
      const int b = i << 4;
      *(uint4*)&Wl[b ^ (((b >> 8) & 7) << 4)] = g[i];
    }
  }
  __syncthreads();

  const int wv = t >> 6, l = t & 63;
  const int lm = l & 15, lk = l >> 4;
  const int r0 = blockIdx.x * 64 + wv * 16;
  int row = r0 + lm;
  if (row >= NN) row = NN - 1;  // clamp; stores are guarded
  const float* fr = feat + (size_t)row * D;

  // A fragments for all 4 k-steps (fp32 load + bf16 convert in-register)
  short8v A[4];
#pragma unroll
  for (int ks = 0; ks < 4; ++ks) {
    const float4 u = *(const float4*)(fr + ks * 32 + lk * 8);
    const float4 v = *(const float4*)(fr + ks * 32 + lk * 8 + 4);
    union { unsigned w[4]; short8v s; } cv;
    cv.w[0] = pk_bf16(u.x, u.y);
    cv.w[1] = pk_bf16(u.z, u.w);
    cv.w[2] = pk_bf16(v.x, v.y);
    cv.w[3] = pk_bf16(v.z, v.w);
    A[ks] = cv.s;
  }

  float4v acc[8];
#pragma unroll
  for (int ct = 0; ct < 8; ++ct) acc[ct] = (float4v){0.f, 0.f, 0.f, 0.f};

#pragma unroll
  for (int ct = 0; ct < 8; ++ct) {
    const int c = ct * 16 + lm;
#pragma unroll
    for (int ks = 0; ks < 4; ++ks) {
      int b = c * 256 + ks * 64 + lk * 16;
      b ^= ((c & 7) << 4);
      const short8v Bf = *(const short8v*)&Wl[b];
      acc[ct] = __builtin_amdgcn_mfma_f32_16x16x32_bf16(A[ks], Bf, acc[ct], 0, 0, 0);
    }
  }

#pragma unroll
  for (int j = 0; j < 4; ++j) {
    const int rr = r0 + lk * 4 + j;
    if (rr < NN) {
      unsigned short* srow = sup + (size_t)rr * D + lm;
#pragma unroll
      for (int ct = 0; ct < 8; ++ct) {
        __hip_bfloat16 h = __float2bfloat16(acc[ct][j]);
        srow[ct * 16] = *(unsigned short*)&h;
      }
    }
  }
}

// ---------------- bucket histogram (196 counters, LDS pre-aggregated) ----------------
__global__ __launch_bounds__(256) void kbhist(const int* __restrict__ dst, int* __restrict__ cnt) {
  __shared__ int h[NB];
  const int t = threadIdx.x;
  for (int i = t; i < NB; i += 256) h[i] = 0;
  __syncthreads();
  const int e0 = blockIdx.x * 4096;
#pragma unroll
  for (int k = 0; k < 16; ++k) {
    const int e = e0 + t + k * 256;
    if (e < NE) atomicAdd(&h[dst[e] >> BSH], 1);
  }
  __syncthreads();
  for (int i = t; i < NB; i += 256) {
    const int c = h[i];
    if (c) atomicAdd(&cnt[i], c);
  }
}

// ---------------- tiny scan over NB buckets ----------------
__global__ __launch_bounds__(256) void kscanNB(const int* __restrict__ cnt,
                                               int* __restrict__ bucketBase,
                                               int* __restrict__ cursorA) {
  __shared__ int s[256];
  const int t = threadIdx.x;
  const int v = (t < NB) ? cnt[t] : 0;
  s[t] = v;
  __syncthreads();
#pragma unroll
  for (int off = 1; off < 256; off <<= 1) {
    const int x = (t >= off) ? s[t - off] : 0;
    __syncthreads();
    s[t] += x;
    __syncthreads();
  }
  if (t < NB) {
    const int excl = s[t] - v;
    bucketBase[t] = excl;
    cursorA[t] = excl;
  }
  if (t == 0) bucketBase[NB] = NE;
}

// ---------------- pass A: multisplit into buckets ----------------
// packed stg word: lo = src | (dst&511)<<17 ; hi = val bits
__global__ __launch_bounds__(256) void kpassA(const int* __restrict__ src,
                                              const int* __restrict__ dst,
                                              const float* __restrict__ val,
                                              int* __restrict__ cursorA,
                                              unsigned long long* __restrict__ stg) {
  __shared__ int h[NB];
  __shared__ int base[NB];
  const int t = threadIdx.x;
  for (int i = t; i < NB; i += 256) h[i] = 0;
  __syncthreads();
  const int e0 = blockIdx.x * 4096;
  int d[16];
#pragma unroll
  for (int k = 0; k < 16; ++k) {
    const int e = e0 + t + k * 256;
    d[k] = (e < NE) ? dst[e] : -1;
    if (d[k] >= 0) atomicAdd(&h[d[k] >> BSH], 1);
  }
  __syncthreads();
  for (int i = t; i < NB; i += 256)
    base[i] = h[i] ? atomicAdd(&cursorA[i], h[i]) : 0;
  __syncthreads();
#pragma unroll
  for (int k = 0; k < 16; ++k) {
    const int e = e0 + t + k * 256;
    if (d[k] >= 0) {
      const int b = d[k] >> BSH;
      const int pos = atomicAdd(&base[b], 1);
      const unsigned lo = (unsigned)src[e] | ((unsigned)(d[k] & 511) << 17);
      const unsigned hi = __float_as_uint(val[e]);
      stg[pos] = (unsigned long long)lo | ((unsigned long long)hi << 32);
    }
  }
}

// ---------------- pass B: per-bucket exact CSR (one block per bucket) ----------------
__global__ __launch_bounds__(256) void kpassB(const unsigned long long* __restrict__ stg,
                                              const int* __restrict__ bucketBase,
                                              int* __restrict__ rowPtr,
                                              unsigned long long* __restrict__ edges) {
  __shared__ int hist[512];
  __shared__ int start[512];
  __shared__ int psum[256];
  const int b = blockIdx.x;
  const int t = threadIdx.x;
  const int beg = bucketBase[b], end = bucketBase[b + 1];
  hist[t] = 0;
  hist[t + 256] = 0;
  __syncthreads();
  for (int i = beg + t; i < end; i += 256)
    atomicAdd(&hist[((unsigned)stg[i] >> 17) & 511], 1);
  __syncthreads();
  const int h0 = hist[2 * t], h1 = hist[2 * t + 1];
  const int p = h0 + h1;
  psum[t] = p;
  __syncthreads();
#pragma unroll
  for (int off = 1; off < 256; off <<= 1) {
    const int x = (t >= off) ? psum[t - off] : 0;
    __syncthreads();
    psum[t] += x;
    __syncthreads();
  }
  const int ex = psum[t] - p;
  start[2 * t] = ex;
  start[2 * t + 1] = ex + h0;
  __syncthreads();
  const int node0 = b << BSH;
  for (int j = t; j < 512; j += 256) {
    const int node = node0 + j;
    if (node < NN) rowPtr[node] = beg + start[j];
  }
  if (b == NB - 1 && t == 0) rowPtr[NN] = NE;
  for (int j = t; j < 512; j += 256) hist[j] = start[j];  // reuse as cursors
  __syncthreads();
  for (int i = beg + t; i < end; i += 256) {
    const unsigned long long pk = stg[i];
    const unsigned lo = (unsigned)pk;
    const int dl = (lo >> 17) & 511;
    const int pos = beg + atomicAdd(&hist[dl], 1);
    edges[pos] = (pk & 0xFFFFFFFF00000000ull) | (unsigned long long)(lo & 0x1FFFFu);
  }
}

// ---------------- gather-aggregate + epilogue ----------------
// 16-lane group per node; lane owns 8 cols (one dwordx4 of bf16x8); 4 nodes/wave.
__global__ __launch_bounds__(256) void kgather(const unsigned short* __restrict__ sup,
                                               const int* __restrict__ rowPtr,
                                               const long long* __restrict__ edges,
                                               const float* __restrict__ feat,
                                               const float* __restrict__ bias,
                                               float* __restrict__ out) {
  const int n = blockIdx.x * 16 + (threadIdx.x >> 4);
  if (n >= NN) return;
  const int gl = threadIdx.x & 15;
  const int beg = rowPtr[n];
  const int end = rowPtr[n + 1];
  float a0 = 0.f, a1 = 0.f, a2 = 0.f, a3 = 0.f, a4 = 0.f, a5 = 0.f, a6 = 0.f, a7 = 0.f;

  for (int base = beg; base < end; base += 16) {
    int cnt = end - base;
    if (cnt > 16) cnt = 16;
    int es = 0, evb = 0;
    if (gl < cnt) {
      const long long e = edges[base + gl];
      es = (int)e;
      evb = (int)(e >> 32);
    }
#pragma unroll 4
    for (int i = 0; i < cnt; ++i) {
      const int si = __shfl(es, i, 16);
      const float vi = __uint_as_float((unsigned)__shfl(evb, i, 16));
      const uint4 r = *(const uint4*)(sup + (size_t)si * D + (gl << 3));
      a0 = fmaf(__uint_as_float(r.x << 16), vi, a0);
      a1 = fmaf(__uint_as_float(r.x & 0xffff0000u), vi, a1);
      a2 = fmaf(__uint_as_float(r.y << 16), vi, a2);
      a3 = fmaf(__uint_as_float(r.y & 0xffff0000u), vi, a3);
      a4 = fmaf(__uint_as_float(r.z << 16), vi, a4);
      a5 = fmaf(__uint_as_float(r.z & 0xffff0000u), vi, a5);
      a6 = fmaf(__uint_as_float(r.w << 16), vi, a6);
      a7 = fmaf(__uint_as_float(r.w & 0xffff0000u), vi, a7);
    }
  }

  const int c = gl << 3;
  const float4 b0 = *(const float4*)(bias + c);
  const float4 b1 = *(const float4*)(bias + c + 4);
  const float* frt = feat + (size_t)n * D + c;
  const float4 f0 = *(const float4*)frt;
  const float4 f1 = *(const float4*)(frt + 4);
  float4 o0, o1;
  o0.x = fmaxf(a0 + b0.x, 0.f) + f0.x;
  o0.y = fmaxf(a1 + b0.y, 0.f) + f0.y;
  o0.z = fmaxf(a2 + b0.z, 0.f) + f0.z;
  o0.w = fmaxf(a3 + b0.w, 0.f) + f0.w;
  o1.x = fmaxf(a4 + b1.x, 0.f) + f1.x;
  o1.y = fmaxf(a5 + b1.y, 0.f) + f1.y;
  o1.z = fmaxf(a6 + b1.z, 0.f) + f1.z;
  o1.w = fmaxf(a7 + b1.w, 0.f) + f1.w;
  float* orow = out + (size_t)n * D + c;
  *(float4*)orow = o0;
  *(float4*)(orow + 4) = o1;
}

extern "C" void kernel_launch(void* const* d_in, const int* in_sizes, int n_in,
                              void* d_out, int out_size, void* d_ws, size_t ws_size,
                              hipStream_t stream) {
  const float* feat = (const float*)d_in[0];
  const int*   esrc = (const int*)d_in[1];
  const int*   edst = (const int*)d_in[2];
  const float* eval = (const float*)d_in[3];
  const float* W    = (const float*)d_in[4];
  const float* bias = (const float*)d_in[5];
  float* out = (float*)d_out;
  char*  ws  = (char*)d_ws;

  unsigned short*     sup        = (unsigned short*)(ws + SUP_OFF);
  int*                rowPtr     = (int*)(ws + ROWPTR_OFF);
  int*                cnt        = (int*)(ws + CNT_OFF);
  int*                bucketBase = (int*)(ws + BB_OFF);
  int*                cursorA    = (int*)(ws + CURA_OFF);
  unsigned short*     Wt         = (unsigned short*)(ws + WT_OFF);
  unsigned long long* stg        = (unsigned long long*)(ws + STG_OFF);
  unsigned long long* edges      = (unsigned long long*)(ws + EDG_OFF);

  // W -> bf16 transposed, then MFMA GEMM: support = feat @ W
  kwconv<<<(D * D + 255) / 256, 256, 0, stream>>>(W, Wt);
  kgemm<<<(NN + 63) / 64, 256, 0, stream>>>(feat, Wt, sup);

  // CSR build via two-level bucket sort
  hipMemsetAsync(cnt, 0, CNT_BY, stream);
  const int nA = (NE + 4095) / 4096;  // 391
  kbhist<<<nA, 256, 0, stream>>>(edst, cnt);
  kscanNB<<<1, 256, 0, stream>>>(cnt, bucketBase, cursorA);
  kpassA<<<nA, 256, 0, stream>>>(esrc, edst, eval, cursorA, stg);
  kpassB<<<NB, 256, 0, stream>>>(stg, bucketBase, rowPtr, edges);

  // gather-aggregate + bias + relu + residual
  kgather<<<(NN + 15) / 16, 256, 0, stream>>>(sup, rowPtr, (const long long*)edges, feat, bias, out);
}

// Round 6
// 157.305 us; speedup vs baseline: 2.4988x; 1.0225x over previous
//
#include <hip/hip_runtime.h>
#include <hip/hip_bf16.h>

#define NN 100000
#define NE 1600000
#define D 128
#define NB 196   // buckets of 512 nodes (dst >> 9)
#define BSH 9

// ---------------- workspace layout ----------------
static constexpr size_t SUP_OFF    = 0;
static constexpr size_t SUP_BYTES  = (((size_t)NN * D * 2) + 15) & ~(size_t)15;   // 25.6 MB bf16
static constexpr size_t ROWPTR_OFF = SUP_OFF + SUP_BYTES;
static constexpr size_t ROWPTR_BY  = (((size_t)(NN + 1) * 4) + 15) & ~(size_t)15;
static constexpr size_t CNT_OFF    = ROWPTR_OFF + ROWPTR_BY;
static constexpr size_t CNT_BY     = (((size_t)NB * 4) + 15) & ~(size_t)15;
static constexpr size_t BB_OFF     = CNT_OFF + CNT_BY;
static constexpr size_t BB_BY      = (((size_t)(NB + 1) * 4) + 15) & ~(size_t)15;
static constexpr size_t CURA_OFF   = BB_OFF + BB_BY;
static constexpr size_t CURA_BY    = (((size_t)NB * 4) + 15) & ~(size_t)15;
static constexpr size_t WT_OFF     = CURA_OFF + CURA_BY;
static constexpr size_t WT_BY      = (size_t)D * D * 2;                            // 32 KB bf16 W^T
static constexpr size_t STG_OFF    = WT_OFF + WT_BY;
static constexpr size_t STG_BY     = (size_t)NE * 8;                               // 12.8 MB
static constexpr size_t EDG_OFF    = STG_OFF + STG_BY;
static constexpr size_t EDG_BY     = (size_t)NE * 4;                               // 6.4 MB (4B records)

typedef __attribute__((ext_vector_type(8))) short short8v;   // 8 bf16 (4 VGPRs)
typedef __attribute__((ext_vector_type(4))) float float4v;   // MFMA C/D + nt-capable f32x4
typedef __attribute__((ext_vector_type(4))) unsigned uint4v; // nt-capable u32x4

__device__ __forceinline__ unsigned pk_bf16(float a, float b) {
  __hip_bfloat16 x = __float2bfloat16(a), y = __float2bfloat16(b);
  return (unsigned)*(unsigned short*)&x | ((unsigned)*(unsigned short*)&y << 16);
}

// ---------------- W prep: Wt[col][k] = bf16(W[k][col]) ----------------
__global__ __launch_bounds__(256) void kwconv(const float* __restrict__ W,
                                              unsigned short* __restrict__ Wt) {
  const int i = blockIdx.x * 256 + threadIdx.x;
  if (i < D * D) {
    const int k = i >> 7, c = i & 127;
    __hip_bfloat16 h = __float2bfloat16(W[i]);
    Wt[c * D + k] = *(unsigned short*)&h;
  }
}

// ---------------- GEMM: support = feat @ W via MFMA bf16 ----------------
__global__ __launch_bounds__(256) void kgemm(const float* __restrict__ feat,
                                             const unsigned short* __restrict__ Wt,
                                             unsigned short* __restrict__ sup) {
  __shared__ char Wl[32768];
  const int t = threadIdx.x;
  {
    const uint4* g = (const uint4*)Wt;
    for (int i = t; i < 2048; i += 256) {
      const int b = i << 4;
      *(uint4*)&Wl[b ^ (((b >> 8) & 7) << 4)] = g[i];
    }
  }
  __syncthreads();

  const int wv = t >> 6, l = t & 63;
  const int lm = l & 15, lk = l >> 4;
  const int r0 = blockIdx.x * 64 + wv * 16;
  int row = r0 + lm;
  if (row >= NN) row = NN - 1;  // clamp; stores are guarded
  const float* fr = feat + (size_t)row * D;

  short8v A[4];
#pragma unroll
  for (int ks = 0; ks < 4; ++ks) {
    const float4 u = *(const float4*)(fr + ks * 32 + lk * 8);
    const float4 v = *(const float4*)(fr + ks * 32 + lk * 8 + 4);
    union { unsigned w[4]; short8v s; } cv;
    cv.w[0] = pk_bf16(u.x, u.y);
    cv.w[1] = pk_bf16(u.z, u.w);
    cv.w[2] = pk_bf16(v.x, v.y);
    cv.w[3] = pk_bf16(v.z, v.w);
    A[ks] = cv.s;
  }

  float4v acc[8];
#pragma unroll
  for (int ct = 0; ct < 8; ++ct) acc[ct] = (float4v){0.f, 0.f, 0.f, 0.f};

#pragma unroll
  for (int ct = 0; ct < 8; ++ct) {
    const int c = ct * 16 + lm;
#pragma unroll
    for (int ks = 0; ks < 4; ++ks) {
      int b = c * 256 + ks * 64 + lk * 16;
      b ^= ((c & 7) << 4);
      const short8v Bf = *(const short8v*)&Wl[b];
      acc[ct] = __builtin_amdgcn_mfma_f32_16x16x32_bf16(A[ks], Bf, acc[ct], 0, 0, 0);
    }
  }

#pragma unroll
  for (int j = 0; j < 4; ++j) {
    const int rr = r0 + lk * 4 + j;
    if (rr < NN) {
      unsigned short* srow = sup + (size_t)rr * D + lm;
#pragma unroll
      for (int ct = 0; ct < 8; ++ct) {
        __hip_bfloat16 h = __float2bfloat16(acc[ct][j]);
        srow[ct * 16] = *(unsigned short*)&h;
      }
    }
  }
}

// ---------------- bucket histogram ----------------
__global__ __launch_bounds__(256) void kbhist(const int* __restrict__ dst, int* __restrict__ cnt) {
  __shared__ int h[NB];
  const int t = threadIdx.x;
  for (int i = t; i < NB; i += 256) h[i] = 0;
  __syncthreads();
  const int e0 = blockIdx.x * 4096;
#pragma unroll
  for (int k = 0; k < 16; ++k) {
    const int e = e0 + t + k * 256;
    if (e < NE) atomicAdd(&h[dst[e] >> BSH], 1);
  }
  __syncthreads();
  for (int i = t; i < NB; i += 256) {
    const int c = h[i];
    if (c) atomicAdd(&cnt[i], c);
  }
}

// ---------------- tiny scan over NB buckets ----------------
__global__ __launch_bounds__(256) void kscanNB(const int* __restrict__ cnt,
                                               int* __restrict__ bucketBase,
                                               int* __restrict__ cursorA) {
  __shared__ int s[256];
  const int t = threadIdx.x;
  const int v = (t < NB) ? cnt[t] : 0;
  s[t] = v;
  __syncthreads();
#pragma unroll
  for (int off = 1; off < 256; off <<= 1) {
    const int x = (t >= off) ? s[t - off] : 0;
    __syncthreads();
    s[t] += x;
    __syncthreads();
  }
  if (t < NB) {
    const int excl = s[t] - v;
    bucketBase[t] = excl;
    cursorA[t] = excl;
  }
  if (t == 0) bucketBase[NB] = NE;
}

// ---------------- pass A: multisplit into buckets ----------------
// packed stg word: lo = src | (dst&511)<<17 ; hi = val fp32 bits
__global__ __launch_bounds__(256) void kpassA(const int* __restrict__ src,
                                              const int* __restrict__ dst,
                                              const float* __restrict__ val,
                                              int* __restrict__ cursorA,
                                              unsigned long long* __restrict__ stg) {
  __shared__ int h[NB];
  __shared__ int base[NB];
  const int t = threadIdx.x;
  for (int i = t; i < NB; i += 256) h[i] = 0;
  __syncthreads();
  const int e0 = blockIdx.x * 4096;
  int d[16];
#pragma unroll
  for (int k = 0; k < 16; ++k) {
    const int e = e0 + t + k * 256;
    d[k] = (e < NE) ? dst[e] : -1;
    if (d[k] >= 0) atomicAdd(&h[d[k] >> BSH], 1);
  }
  __syncthreads();
  for (int i = t; i < NB; i += 256)
    base[i] = h[i] ? atomicAdd(&cursorA[i], h[i]) : 0;
  __syncthreads();
#pragma unroll
  for (int k = 0; k < 16; ++k) {
    const int e = e0 + t + k * 256;
    if (d[k] >= 0) {
      const int b = d[k] >> BSH;
      const int pos = atomicAdd(&base[b], 1);
      const unsigned lo = (unsigned)src[e] | ((unsigned)(d[k] & 511) << 17);
      const unsigned hi = __float_as_uint(val[e]);
      stg[pos] = (unsigned long long)lo | ((unsigned long long)hi << 32);
    }
  }
}

// ---------------- pass B: per-bucket exact CSR; 4B edge records ----------------
// record = src(17b) | bf16(val)<<17  (val in [0,1) -> sign bit 0, fits 15b)
__global__ __launch_bounds__(256) void kpassB(const unsigned long long* __restrict__ stg,
                                              const int* __restrict__ bucketBase,
                                              int* __restrict__ rowPtr,
                                              unsigned* __restrict__ edges) {
  __shared__ int hist[512];
  __shared__ int start[512];
  __shared__ int psum[256];
  const int b = blockIdx.x;
  const int t = threadIdx.x;
  const int beg = bucketBase[b], end = bucketBase[b + 1];
  hist[t] = 0;
  hist[t + 256] = 0;
  __syncthreads();
  for (int i = beg + t; i < end; i += 256)
    atomicAdd(&hist[((unsigned)stg[i] >> 17) & 511], 1);
  __syncthreads();
  const int h0 = hist[2 * t], h1 = hist[2 * t + 1];
  const int p = h0 + h1;
  psum[t] = p;
  __syncthreads();
#pragma unroll
  for (int off = 1; off < 256; off <<= 1) {
    const int x = (t >= off) ? psum[t - off] : 0;
    __syncthreads();
    psum[t] += x;
    __syncthreads();
  }
  const int ex = psum[t] - p;
  start[2 * t] = ex;
  start[2 * t + 1] = ex + h0;
  __syncthreads();
  const int node0 = b << BSH;
  for (int j = t; j < 512; j += 256) {
    const int node = node0 + j;
    if (node < NN) rowPtr[node] = beg + start[j];
  }
  if (b == NB - 1 && t == 0) rowPtr[NN] = NE;
  for (int j = t; j < 512; j += 256) hist[j] = start[j];  // reuse as cursors
  __syncthreads();
  for (int i = beg + t; i < end; i += 256) {
    const unsigned long long pk = stg[i];
    const unsigned lo = (unsigned)pk;
    const int dl = (lo >> 17) & 511;
    const int pos = beg + atomicAdd(&hist[dl], 1);
    __hip_bfloat16 hv = __float2bfloat16(__uint_as_float((unsigned)(pk >> 32)));
    edges[pos] = (lo & 0x1FFFFu) | ((unsigned)*(unsigned short*)&hv << 17);
  }
}

// ---------------- gather-aggregate + epilogue ----------------
// 16-lane group per node; lane owns 8 cols; 8-row preload batches; nt streaming.
__global__ __launch_bounds__(256) void kgather(const unsigned short* __restrict__ sup,
                                               const int* __restrict__ rowPtr,
                                               const unsigned* __restrict__ edges,
                                               const float* __restrict__ feat,
                                               const float* __restrict__ bias,
                                               float* __restrict__ out) {
  const int n = blockIdx.x * 16 + (threadIdx.x >> 4);
  if (n >= NN) return;
  const int gl = threadIdx.x & 15;
  const int beg = rowPtr[n];
  const int end = rowPtr[n + 1];
  float a0 = 0.f, a1 = 0.f, a2 = 0.f, a3 = 0.f, a4 = 0.f, a5 = 0.f, a6 = 0.f, a7 = 0.f;

  const char* supb = (const char*)sup;
  const unsigned glo = (unsigned)(gl << 4);

  unsigned w = 0;
  if (beg + gl < end) w = __builtin_nontemporal_load(edges + beg + gl);

  for (int base = beg; base < end; base += 16) {
    int cnt = end - base;
    if (cnt > 16) cnt = 16;
    const unsigned wc = w;
    if (base + 16 + gl < end) w = __builtin_nontemporal_load(edges + base + 16 + gl);

    int i = 0;
    for (; i + 8 <= cnt; i += 8) {
      const unsigned r0 = __shfl(wc, i + 0, 16);
      const unsigned r1 = __shfl(wc, i + 1, 16);
      const unsigned r2 = __shfl(wc, i + 2, 16);
      const unsigned r3 = __shfl(wc, i + 3, 16);
      const unsigned r4 = __shfl(wc, i + 4, 16);
      const unsigned r5 = __shfl(wc, i + 5, 16);
      const unsigned r6 = __shfl(wc, i + 6, 16);
      const unsigned r7 = __shfl(wc, i + 7, 16);
      const uint4v q0 = *(const uint4v*)(supb + ((r0 & 0x1FFFFu) << 8) + glo);
      const uint4v q1 = *(const uint4v*)(supb + ((r1 & 0x1FFFFu) << 8) + glo);
      const uint4v q2 = *(const uint4v*)(supb + ((r2 & 0x1FFFFu) << 8) + glo);
      const uint4v q3 = *(const uint4v*)(supb + ((r3 & 0x1FFFFu) << 8) + glo);
      const uint4v q4 = *(const uint4v*)(supb + ((r4 & 0x1FFFFu) << 8) + glo);
      const uint4v q5 = *(const uint4v*)(supb + ((r5 & 0x1FFFFu) << 8) + glo);
      const uint4v q6 = *(const uint4v*)(supb + ((r6 & 0x1FFFFu) << 8) + glo);
      const uint4v q7 = *(const uint4v*)(supb + ((r7 & 0x1FFFFu) << 8) + glo);
#define ACC8(q, rr)                                                        \
      {                                                                    \
        const float vv = __uint_as_float((rr >> 17) << 16);                \
        a0 = fmaf(__uint_as_float(q.x << 16), vv, a0);                     \
        a1 = fmaf(__uint_as_float(q.x & 0xffff0000u), vv, a1);             \
        a2 = fmaf(__uint_as_float(q.y << 16), vv, a2);                     \
        a3 = fmaf(__uint_as_float(q.y & 0xffff0000u), vv, a3);             \
        a4 = fmaf(__uint_as_float(q.z << 16), vv, a4);                     \
        a5 = fmaf(__uint_as_float(q.z & 0xffff0000u), vv, a5);             \
        a6 = fmaf(__uint_as_float(q.w << 16), vv, a6);                     \
        a7 = fmaf(__uint_as_float(q.w & 0xffff0000u), vv, a7);             \
      }
      ACC8(q0, r0) ACC8(q1, r1) ACC8(q2, r2) ACC8(q3, r3)
      ACC8(q4, r4) ACC8(q5, r5) ACC8(q6, r6) ACC8(q7, r7)
    }
    for (; i < cnt; ++i) {
      const unsigned rr = __shfl(wc, i, 16);
      const uint4v q = *(const uint4v*)(supb + ((rr & 0x1FFFFu) << 8) + glo);
      ACC8(q, rr)
    }
#undef ACC8
  }

  const int c = gl << 3;
  const float4v b0 = *(const float4v*)(bias + c);
  const float4v b1 = *(const float4v*)(bias + c + 4);
  const float* frt = feat + (size_t)n * D + c;
  const float4v f0 = __builtin_nontemporal_load((const float4v*)frt);
  const float4v f1 = __builtin_nontemporal_load((const float4v*)(frt + 4));
  float4v o0, o1;
  o0.x = fmaxf(a0 + b0.x, 0.f) + f0.x;
  o0.y = fmaxf(a1 + b0.y, 0.f) + f0.y;
  o0.z = fmaxf(a2 + b0.z, 0.f) + f0.z;
  o0.w = fmaxf(a3 + b0.w, 0.f) + f0.w;
  o1.x = fmaxf(a4 + b1.x, 0.f) + f1.x;
  o1.y = fmaxf(a5 + b1.y, 0.f) + f1.y;
  o1.z = fmaxf(a6 + b1.z, 0.f) + f1.z;
  o1.w = fmaxf(a7 + b1.w, 0.f) + f1.w;
  float* orow = out + (size_t)n * D + c;
  __builtin_nontemporal_store(o0, (float4v*)orow);
  __builtin_nontemporal_store(o1, (float4v*)(orow + 4));
}

extern "C" void kernel_launch(void* const* d_in, const int* in_sizes, int n_in,
                              void* d_out, int out_size, void* d_ws, size_t ws_size,
                              hipStream_t stream) {
  const float* feat = (const float*)d_in[0];
  const int*   esrc = (const int*)d_in[1];
  const int*   edst = (const int*)d_in[2];
  const float* eval = (const float*)d_in[3];
  const float* W    = (const float*)d_in[4];
  const float* bias = (const float*)d_in[5];
  float* out = (float*)d_out;
  char*  ws  = (char*)d_ws;

  unsigned short*     sup        = (unsigned short*)(ws + SUP_OFF);
  int*                rowPtr     = (int*)(ws + ROWPTR_OFF);
  int*                cnt        = (int*)(ws + CNT_OFF);
  int*                bucketBase = (int*)(ws + BB_OFF);
  int*                cursorA    = (int*)(ws + CURA_OFF);
  unsigned short*     Wt         = (unsigned short*)(ws + WT_OFF);
  unsigned long long* stg        = (unsigned long long*)(ws + STG_OFF);
  unsigned*           edges      = (unsigned*)(ws + EDG_OFF);

  // W -> bf16 transposed, then MFMA GEMM: support = feat @ W
  kwconv<<<(D * D + 255) / 256, 256, 0, stream>>>(W, Wt);
  kgemm<<<(NN + 63) / 64, 256, 0, stream>>>(feat, Wt, sup);

  // CSR build via two-level bucket sort
  hipMemsetAsync(cnt, 0, CNT_BY, stream);
  const int nA = (NE + 4095) / 4096;  // 391
  kbhist<<<nA, 256, 0, stream>>>(edst, cnt);
  kscanNB<<<1, 256, 0, stream>>>(cnt, bucketBase, cursorA);
  kpassA<<<nA, 256, 0, stream>>>(esrc, edst, eval, cursorA, stg);
  kpassB<<<NB, 256, 0, stream>>>(stg, bucketBase, rowPtr, edges);

  // gather-aggregate + bias + relu + residual
  kgather<<<(NN + 15) / 16, 256, 0, stream>>>(sup, rowPtr, edges, feat, bias, out);
}